// Round 13
// baseline (125.302 us; speedup 1.0000x reference)
//
#include <hip/hip_runtime.h>
#include <math.h>

// MutualInformationLoss on MI355X — round 13.
// K1 is at its LDS-pipe floor (~24 us ideal, ~35-40 actual; r8-r12 all within
// noise). Tail de-fat: K2 writes per-group fp64 slabs (no atomics, no memset
// dispatch); K3 sums 24 contiguous slabs/batch (406 KB coalesced) + marginals
// + MI. 3 dispatches total, fully deterministic.

#define NBINS   23
#define NCELLS  529
#define NBATCH  4
#define NVOX    884736
#define PBLK    384               // blocks per batch: 384 * 2304 = 884736
#define VPB     2304              // voxels per block
#define VPW     576               // voxels per wave (9 chunks of 64)
#define NCHUNK  9
#define RPB     16                // partial rows per reduce block
#define RBLK    (PBLK / RPB)      // 24
#define RS      72                // image row stride in halves (144 B)
#define IMGB    (23 * RS * 2)     // 3312 B per image (23 rows, 16B-multiple)
#define WREG    (2 * IMGB)        // 6624 B per wave (A + B images)

typedef float    vf4  __attribute__((ext_vector_type(4)));
typedef _Float16 h8   __attribute__((ext_vector_type(8)));
typedef float    f16v __attribute__((ext_vector_type(16)));

#define G1 0.13533528f        // exp(-2)
#define G2 3.3546263e-4f      // exp(-8)
#define G3 1.5229979e-8f      // exp(-18)

// 7-bin window at rows i0..i0+6 via factored Gaussian (2 exp + 1 rcp):
//   w(t) = W0 * R^t * G(t), W0=exp(-968 v^2), R=exp(88 v), v = x - c_mid
__device__ __forceinline__ float window7(float x, int& i0, float* w)
{
    x = fminf(fmaxf(x, 0.0f), 1.0f);
    int ka = (int)floorf(fmaf(x, 22.0f, 0.5f));
    i0 = min(max(ka - 3, 0), 16);
    float v  = fmaf((float)(i0 + 3), -(1.0f / 22.0f), x);
    float W0 = __expf(-968.0f * v * v);
    float R  = __expf(88.0f * v);
    float Ri = __builtin_amdgcn_rcpf(R);
    float R2 = R * R,   R3 = R2 * R;
    float R2i = Ri * Ri, R3i = R2i * Ri;
    w[0] = W0 * (R3i * G3);
    w[1] = W0 * (R2i * G2);
    w[2] = W0 * (Ri  * G1);
    w[3] = W0;
    w[4] = W0 * (R   * G1);
    w[5] = W0 * (R2  * G2);
    w[6] = W0 * (R3  * G3);
    return ((w[0] + w[6]) + (w[1] + w[5])) + ((w[2] + w[4]) + w[3]);
}

// ---------------- K1: fused Parzen-window + MFMA joint histogram ----------------
__global__ __launch_bounds__(256, 6)      // 6 blocks/CU (LDS 26.5 KB)
void mi_mfma(const float* __restrict__ pred,
             const float* __restrict__ targ,
             float* __restrict__ partial)      // [NBATCH*PBLK][NCELLS]
{
    __shared__ __align__(16) char smem[4 * WREG];   // 26496 B

    const int p    = blockIdx.x;
    const int b    = blockIdx.y;
    const int wv   = threadIdx.x >> 6;
    const int lane = threadIdx.x & 63;
    const int m    = lane & 31;               // tile row for fragment reads
    const int h    = lane >> 5;               // k-half selector
    const int mr   = m < NBINS ? m : NBINS - 1;  // clamped read row (m>=23
                                              // feeds C rows/cols discarded)

    char* wbase = smem + wv * WREG;
    _Float16* Aimg = (_Float16*)wbase;
    _Float16* Bimg = (_Float16*)(wbase + IMGB);
    const _Float16* Ard = Aimg + mr * RS + 8 * h;
    const _Float16* Brd = Bimg + mr * RS + 8 * h;

    const float* __restrict__ px =
        pred + (size_t)b * NVOX + (size_t)p * VPB + (size_t)wv * VPW;
    const float* __restrict__ py =
        targ + (size_t)b * NVOX + (size_t)p * VPB + (size_t)wv * VPW;

    // upfront preload: 9 voxels/lane (chunk c uses element c; the voxel->k
    // permutation is shared by A and B, so the inner product is unchanged)
    vf4 X1 = *(const vf4*)(px + 4 * lane);
    vf4 X2 = *(const vf4*)(px + 256 + 4 * lane);
    float x8 = px[512 + lane];
    vf4 Y1 = *(const vf4*)(py + 4 * lane);
    vf4 Y2 = *(const vf4*)(py + 256 + 4 * lane);
    float y8 = py[512 + lane];
    float xs[NCHUNK] = {X1.x, X1.y, X1.z, X1.w, X2.x, X2.y, X2.z, X2.w, x8};
    float ys[NCHUNK] = {Y1.x, Y1.y, Y1.z, Y1.w, Y2.x, Y2.y, Y2.z, Y2.w, y8};

    f16v acc = {};

    #pragma unroll
    for (int c = 0; c < NCHUNK; ++c) {
        // zero both images' 23 rows: one contiguous 6624 B span
        vf4 z = {0.f, 0.f, 0.f, 0.f};
        #pragma unroll
        for (int it = 0; it < 6; ++it)
            *(vf4*)(wbase + (it * 64 + lane) * 16) = z;
        if (lane < 30)
            *(vf4*)(wbase + (384 + lane) * 16) = z;

        int ia, ja;
        float wa[7], wb[7];
        float sa = window7(xs[c], ia, wa);
        float sb = window7(ys[c], ja, wb);
        float inv = __builtin_amdgcn_rcpf(sa * sb);   // fold both norms onto A

        #pragma unroll
        for (int t = 0; t < 7; ++t) {
            Aimg[(ia + t) * RS + lane] = (_Float16)(wa[t] * inv);  // RNE cvt
            Bimg[(ja + t) * RS + lane] = (_Float16)wb[t];
        }

        // 4 k-steps of 32x32x16; reads bank-balanced (bank base 4m+4h+8s)
        #pragma unroll
        for (int s = 0; s < 4; ++s) {
            h8 Af = *(const h8*)(Ard + 16 * s);
            h8 Bf = *(const h8*)(Brd + 16 * s);
            acc = __builtin_amdgcn_mfma_f32_32x32x16_f16(Af, Bf, acc, 0, 0, 0);
        }
    }

    // epilogue: C layout col=lane&31, row=(reg&3)+8*(reg>>2)+4*h (m74/m101)
    float* tile = (float*)wbase;               // reuse wave region (4224 B)
    #pragma unroll
    for (int r = 0; r < 16; ++r) {
        int row = (r & 3) + 8 * (r >> 2) + 4 * h;
        tile[row * 33 + m] = acc[r];
    }
    __syncthreads();
    for (int c = threadIdx.x; c < NCELLS; c += 256) {
        int i = c / NBINS, j = c % NBINS;
        float s = 0.0f;
        #pragma unroll
        for (int w = 0; w < 4; ++w)
            s += ((const float*)(smem + w * WREG))[i * 33 + j];
        partial[((size_t)(b * PBLK + p)) * NCELLS + c] = s;   // coalesced rows
    }
}

// ------ K2: coalesced fp64 reduction -> per-group slabs (no atomics) ------
__global__ __launch_bounds__(256)
void mi_reduce(const float* __restrict__ partial, double* __restrict__ slab)
{
    const int g = blockIdx.x;                 // 0..RBLK-1
    const int b = blockIdx.y;
    const int t = threadIdx.x;
    const float* __restrict__ src =
        partial + ((size_t)b * PBLK + (size_t)g * RPB) * NCELLS;

    double a0 = 0.0, a1 = 0.0, a2 = 0.0;
    #pragma unroll
    for (int p = 0; p < RPB; ++p) {
        const float* __restrict__ row = src + (size_t)p * NCELLS;
        a0 += (double)row[t];
        a1 += (double)row[256 + t];
        if (t < NCELLS - 512) a2 += (double)row[512 + t];
    }
    double* __restrict__ dst = slab + ((size_t)b * RBLK + g) * NCELLS;
    dst[t]       = a0;
    dst[256 + t] = a1;
    if (t < NCELLS - 512) dst[512 + t] = a2;
}

// ---------------- K3: slab sum + fp64 marginals + MI ----------------
__global__ __launch_bounds__(256)
void mi_final(const double* __restrict__ slab, float* __restrict__ out)
{
    __shared__ double s_pab[NCELLS];
    __shared__ double s_pa[NBINS];
    __shared__ double s_pb[NBINS];
    __shared__ double s_red[4];

    double total = 0.0;
    for (int b = 0; b < NBATCH; ++b) {
        const double* __restrict__ sb_ = slab + (size_t)b * RBLK * NCELLS;
        for (int c = threadIdx.x; c < NCELLS; c += 256) {
            double s = 0.0;
            #pragma unroll 4
            for (int g = 0; g < RBLK; ++g)
                s += sb_[(size_t)g * NCELLS + c];
            s_pab[c] = s * (1.0 / (double)NVOX);
        }
        __syncthreads();
        if (threadIdx.x < NBINS) {
            const int i = threadIdx.x;
            double r = 0.0, cl = 0.0;
            for (int j = 0; j < NBINS; ++j) {
                r  += s_pab[i * NBINS + j];
                cl += s_pab[j * NBINS + i];
            }
            s_pa[i] = r; s_pb[i] = cl;
        }
        __syncthreads();
        double t = 0.0;
        for (int c = threadIdx.x; c < NCELLS; c += 256) {
            double pv   = s_pab[c];
            double papb = s_pa[c / NBINS] * s_pb[c % NBINS];
            t += pv * log((pv + 1e-7) / (papb + 1e-7) + 1e-7);
        }
        #pragma unroll
        for (int off = 32; off > 0; off >>= 1) t += __shfl_down(t, off, 64);
        if ((threadIdx.x & 63) == 0) s_red[threadIdx.x >> 6] = t;
        __syncthreads();
        if (threadIdx.x == 0) total += s_red[0] + s_red[1] + s_red[2] + s_red[3];
        __syncthreads();
    }
    if (threadIdx.x == 0) out[0] = (float)(-total * 0.25);
}

extern "C" void kernel_launch(void* const* d_in, const int* in_sizes, int n_in,
                              void* d_out, int out_size, void* d_ws, size_t ws_size,
                              hipStream_t stream)
{
    const float* pred = (const float*)d_in[0];
    const float* targ = (const float*)d_in[1];
    float* out = (float*)d_out;
    char* ws = (char*)d_ws;

    // layout: [partial: NBATCH*PBLK*NCELLS f32 = 3.25 MB]
    //         [slab: NBATCH*RBLK*NCELLS f64 = 406 KB]
    const size_t off_partial = 0;
    const size_t off_slab    =
        ((size_t)NBATCH * PBLK * NCELLS * 4 + 255) & ~(size_t)255;

    float*  partial = (float*)(ws + off_partial);
    double* slab    = (double*)(ws + off_slab);

    // all workspace slots fully written each call — no memset needed
    mi_mfma  <<<dim3(PBLK, NBATCH), 256, 0, stream>>>(pred, targ, partial);
    mi_reduce<<<dim3(RBLK, NBATCH), 256, 0, stream>>>(partial, slab);
    mi_final <<<1, 256, 0, stream>>>(slab, out);
}